// Round 1
// 381.566 us; speedup vs baseline: 1.0204x; 1.0204x over previous
//
#include <hip/hip_runtime.h>

// ClusteredLinformerAttention — round 4: 256x256 deep-pipelined GEMM
// (counted-vmcnt ring buffer, T2 LDS swizzle, T5 setprio) replacing the
// m97-style 128x128 2-barrier GEMM for both QKV and out-proj.
// B=8 N=4096 D=512 H=8 R=256 DEPTH=64.
// MFMA v_mfma_f32_16x16x32_bf16; layouts (m89/m120):
//   A[m=lane&15][k=quad*8+j], B[k=quad*8+j][n=lane&15], C/D: col=lane&15, row=quad*4+reg.

typedef __bf16 bf16;
typedef __attribute__((ext_vector_type(8))) __bf16 bf16x8;
typedef __attribute__((ext_vector_type(8))) unsigned short ushort8;
typedef __attribute__((ext_vector_type(4))) float floatx4;

#define MFMA16(a, b, c) __builtin_amdgcn_mfma_f32_16x16x32_bf16((a), (b), (c), 0, 0, 0)

static __device__ __forceinline__ unsigned short bf_bits(float f) {
  unsigned u = __builtin_bit_cast(unsigned, f);
  u += 0x7fffu + ((u >> 16) & 1u);   // RNE
  return (unsigned short)(u >> 16);
}
static __device__ __forceinline__ bf16 f2bf(float f) {
  unsigned short s = bf_bits(f);
  return __builtin_bit_cast(bf16, s);
}
static __device__ __forceinline__ float bf2f(bf16 v) {
  unsigned u = (unsigned)__builtin_bit_cast(unsigned short, v) << 16;
  return __builtin_bit_cast(float, u);
}
// async global->LDS, 16B/lane; LDS dest = wave-uniform base + lane*16.
static __device__ __forceinline__ void async_copy16(const void* g, void* l) {
  __builtin_amdgcn_global_load_lds((const __attribute__((address_space(1))) void*)g,
                                   (__attribute__((address_space(3))) void*)l, 16, 0, 0);
}

// ---------------------------------------------------------------------------
// fp32 -> bf16 bulk convert (x). 8 elems/thread.
// ---------------------------------------------------------------------------
__global__ void cvt_bf16_kernel(const float* __restrict__ src, bf16* __restrict__ dst) {
  long i = ((long)blockIdx.x * 256 + threadIdx.x) * 8;
  float4 a = *(const float4*)(src + i);
  float4 b = *(const float4*)(src + i + 4);
  ushort8 o;
  o[0] = bf_bits(a.x); o[1] = bf_bits(a.y); o[2] = bf_bits(a.z); o[3] = bf_bits(a.w);
  o[4] = bf_bits(b.x); o[5] = bf_bits(b.y); o[6] = bf_bits(b.z); o[7] = bf_bits(b.w);
  *(ushort8*)(dst + i) = o;
}

// ---------------------------------------------------------------------------
// Batched weight transpose: z selects (src,dst). dst[n*512+k] = bf16(src[k*512+n]).
// ---------------------------------------------------------------------------
__global__ void transpose_w4_kernel(const float* __restrict__ wq, const float* __restrict__ wk,
                                    const float* __restrict__ wv, const float* __restrict__ wd,
                                    bf16* __restrict__ Wt, bf16* __restrict__ wdT) {
  const int z = blockIdx.z;
  const float* src = z == 0 ? wq : (z == 1 ? wk : (z == 2 ? wv : wd));
  bf16* dst = z < 3 ? Wt + (long)z * 262144 : wdT;
  __shared__ float tile[32][33];
  const int k0 = blockIdx.x * 32, n0 = blockIdx.y * 32;
  const int tx = threadIdx.x, ty = threadIdx.y;   // (32, 8)
#pragma unroll
  for (int i = ty; i < 32; i += 8)
    tile[i][tx] = src[(long)(k0 + i) * 512 + n0 + tx];
  __syncthreads();
#pragma unroll
  for (int i = ty; i < 32; i += 8)
    dst[(long)(n0 + i) * 512 + k0 + tx] = f2bf(tile[tx][i]);
}

// ---------------------------------------------------------------------------
// E/F transpose, z = tensor*8 + head: dst[(h,r),n] = bf16(src[h,n,r]).
// ---------------------------------------------------------------------------
__global__ void transpose_ef_kernel(const float* __restrict__ E, const float* __restrict__ F,
                                    bf16* __restrict__ Et, bf16* __restrict__ Ft) {
  const int z = blockIdx.z, h = z & 7;
  const float* src = (z < 8 ? E : F) + (long)h * 4096 * 256;
  bf16* dst = (z < 8 ? Et : Ft) + (long)h * 256 * 4096;
  __shared__ float tile[32][33];
  const int k0 = blockIdx.x * 32, n0 = blockIdx.y * 32;   // k0: n-dim(4096), n0: r-dim(256)
  const int tx = threadIdx.x, ty = threadIdx.y;
#pragma unroll
  for (int i = ty; i < 32; i += 8)
    tile[i][tx] = src[(long)(k0 + i) * 256 + n0 + tx];
  __syncthreads();
#pragma unroll
  for (int i = ty; i < 32; i += 8)
    dst[(long)(n0 + i) * 4096 + k0 + tx] = f2bf(tile[tx][i]);
}

// ---------------------------------------------------------------------------
// 256x256 GEMM, K=512, C = A(M,512)*Bt(N,512)^T — counted-vmcnt deep pipeline.
// 8 waves (2M x 4N), per-wave 128x64 output (acc[8][4] f32x4 = 128 VGPR).
// K split into 16 sub-tiles of BK=32; 4-slot LDS ring buffer (A and B each
// [4][256][32] bf16 = 64 KiB; 128 KiB dynamic LDS total), prefetch distance 3.
// Per sub-tile: 12 ds_read_b128 + 32 MFMA + 4 global_load_lds, ONE raw
// s_barrier with s_waitcnt vmcnt(8) (counted, never 0 until tail).
// LDS chunk-swizzle: 16B slot c' = c ^ ((row>>1)&3) applied on BOTH sides:
// pre-swizzled global source (gload_lds dest stays linear, m104/m231) and the
// ds_read address -> 2-way (free) bank access on the stride-64B rows.
// XCD swizzle: p = lin&7 owns a contiguous m-band; A-rows stay hot in its L2.
// MODE 0: N=1536 (NB=6), split-write q/k/v bf16. MODE 1: N=512 (NB=2), fp32+bias.
// ---------------------------------------------------------------------------
template <int MODE>
__global__ __launch_bounds__(512, 2) void gemm256_kernel(
    const bf16* __restrict__ A, const bf16* __restrict__ Bt,
    bf16* __restrict__ oq, bf16* __restrict__ ok, bf16* __restrict__ ov,
    float* __restrict__ of, const float* __restrict__ bias) {
  constexpr int NBt = MODE == 0 ? 6 : 2;
  extern __shared__ __align__(16) char smem[];   // [A:65536][B:65536]
  const int lin = blockIdx.x;
  const int p = lin & 7, q = lin >> 3;
  const int m0 = (p * 16 + q / NBt) * 256, n0 = (q % NBt) * 256;
  const int t = threadIdx.x;
  const int w = t >> 6, l = t & 63, quad = l >> 4, lc = l & 15;
  const int wr = w >> 2, wc = w & 3;   // 2 (M) x 4 (N)

  // --- staging addressing: wave w stages rows [j*128 + w*16, +16) per instr.
  // LDS linear (row, c=lane&3); source chunk pre-swizzled: q = c ^ ((row>>1)&3)
  // = (l&3) ^ ((l>>3)&3) since w*16, j*128 are 0 mod 16.
  const int srow = w * 16 + (l >> 2);
  const int sq = (l & 3) ^ ((l >> 3) & 3);
  const bf16* gA0 = A + (long)(m0 + srow) * 512 + sq * 8;
  const bf16* gB0 = Bt + (long)(n0 + srow) * 512 + sq * 8;
  bf16* AsW = (bf16*)smem + w * 512;             // + buf*8192 + j*4096 (elems)
  bf16* BsW = (bf16*)(smem + 65536) + w * 512;

  // --- read addressing (bytes within a buffer): row*64 + swizzled 16B slot.
  // frag row = {wr*128|wc*64} + mt*16 + lc  ->  (row>>1)&3 == (lc>>1)&3.
  const int swz = (quad ^ ((lc >> 1) & 3)) << 4;
  const int a_rd = (wr * 128 + lc) * 64 + swz;
  const int b_rd = (wc * 64 + lc) * 64 + swz;

  floatx4 acc[8][4] = {};

#define STAGE_A(s_, buf_)                                              \
  do {                                                                 \
    async_copy16(gA0 + (s_) * 32, AsW + (buf_) * 8192);                \
    async_copy16(gA0 + 65536l + (s_) * 32, AsW + (buf_) * 8192 + 4096);\
  } while (0)
#define STAGE_B(s_, buf_)                                              \
  do {                                                                 \
    async_copy16(gB0 + (s_) * 32, BsW + (buf_) * 8192);                \
    async_copy16(gB0 + 65536l + (s_) * 32, BsW + (buf_) * 8192 + 4096);\
  } while (0)

  // prologue: stage sub-tiles 0,1,2 (4 loads/wave each)
  STAGE_A(0, 0); STAGE_B(0, 0);
  STAGE_A(1, 1); STAGE_B(1, 1);
  STAGE_A(2, 2); STAGE_B(2, 2);
  asm volatile("s_waitcnt vmcnt(8)" ::: "memory");   // sub-tile 0 landed (mine)
  __builtin_amdgcn_sched_barrier(0);
  __builtin_amdgcn_s_barrier();                      // everyone's sub-tile 0
  __builtin_amdgcn_sched_barrier(0);

#pragma unroll
  for (int s = 0; s < 16; ++s) {
    const int buf = s & 3, tb = (s + 3) & 3;   // tb == (s-1)&3: its reads are done
    const char* Ab = smem + buf * 16384;
    const char* Bb = smem + 65536 + buf * 16384;
    bf16x8 af[4], bfr[4];
    // phase A: B frags (all nt) + A frags mt 0..3; issue A staging for s+3
#pragma unroll
    for (int nt = 0; nt < 4; ++nt)
      bfr[nt] = *(const bf16x8*)(Bb + b_rd + nt * 1024);
#pragma unroll
    for (int mt = 0; mt < 4; ++mt)
      af[mt] = *(const bf16x8*)(Ab + a_rd + mt * 1024);
    if (s < 13) STAGE_A(s + 3, tb);
    __builtin_amdgcn_s_setprio(1);
#pragma unroll
    for (int mt = 0; mt < 4; ++mt)
#pragma unroll
      for (int nt = 0; nt < 4; ++nt)
        acc[mt][nt] = MFMA16(af[mt], bfr[nt], acc[mt][nt]);
    __builtin_amdgcn_s_setprio(0);
    // phase B: A frags mt 4..7 (B frags reused); issue B staging for s+3
#pragma unroll
    for (int mt = 0; mt < 4; ++mt)
      af[mt] = *(const bf16x8*)(Ab + a_rd + (mt + 4) * 1024);
    if (s < 13) STAGE_B(s + 3, tb);
    __builtin_amdgcn_s_setprio(1);
#pragma unroll
    for (int mt = 0; mt < 4; ++mt)
#pragma unroll
      for (int nt = 0; nt < 4; ++nt)
        acc[mt + 4][nt] = MFMA16(af[mt], bfr[nt], acc[mt + 4][nt]);
    __builtin_amdgcn_s_setprio(0);
    // boundary: ensure staging(s+1) landed everywhere. Counted wait:
    // in flight after staging(s+1) = sub-tiles s+2,s+3 = 8 loads (tail: 4/0).
    if (s < 15) {
      if (s <= 12)      { asm volatile("s_waitcnt vmcnt(8)" ::: "memory"); }
      else if (s == 13) { asm volatile("s_waitcnt vmcnt(4)" ::: "memory"); }
      else              { asm volatile("s_waitcnt vmcnt(0)" ::: "memory"); }
      __builtin_amdgcn_sched_barrier(0);
      __builtin_amdgcn_s_barrier();
      __builtin_amdgcn_sched_barrier(0);
    }
  }
#undef STAGE_A
#undef STAGE_B

  if (MODE == 0) {
    const int which = n0 >> 9, nb = n0 & 511;
    bf16* dst = which == 0 ? oq : (which == 1 ? ok : ov);
#pragma unroll
    for (int mt = 0; mt < 8; ++mt)
#pragma unroll
      for (int nt = 0; nt < 4; ++nt)
#pragma unroll
        for (int i = 0; i < 4; ++i) {
          int row = m0 + wr * 128 + mt * 16 + quad * 4 + i;
          int col = nb + wc * 64 + nt * 16 + lc;
          dst[(long)row * 512 + col] = f2bf(acc[mt][nt][i]);
        }
  } else {
#pragma unroll
    for (int mt = 0; mt < 8; ++mt)
#pragma unroll
      for (int nt = 0; nt < 4; ++nt)
#pragma unroll
        for (int i = 0; i < 4; ++i) {
          int row = m0 + wr * 128 + mt * 16 + quad * 4 + i;
          int col = n0 + wc * 64 + nt * 16 + lc;
          of[(long)row * 512 + col] = acc[mt][nt][i] + bias[col];
        }
  }
}

// ---------------------------------------------------------------------------
// Projection (atomic-free, 4 n-chunk bf16 partials):
//  z=0: kp_part[nc][bh][r][d] = sum_n k[b,n,h,d] * E[h,n,r]
//  z=1: vp_part[nc][bh][d][r] = sum_n v[b,n,h,d] * F[h,n,r]
// Big side (E/F^T, 256 x k) via global_load_lds; small side (K/V) LDS-
// transposed with XOR swizzle (2-way max on store & read).
// ---------------------------------------------------------------------------
__global__ __launch_bounds__(256) void proj_kernel(
    const bf16* __restrict__ Et_g, const bf16* __restrict__ Ft_g,
    const bf16* __restrict__ kb, const bf16* __restrict__ vb,
    bf16* __restrict__ kp_part, bf16* __restrict__ vp_part) {
  const int z = blockIdx.z;
  const bf16* Big = z ? Ft_g : Et_g;
  const bf16* src = z ? vb : kb;
  bf16* out = z ? vp_part : kp_part;
  const int bh = blockIdx.y, b = bh >> 3, h = bh & 7;
  const int nbase = blockIdx.x * 1024;
  __shared__ bf16 Eb[256][64];
  __shared__ bf16 Kt[64][72];
  const int t = threadIdx.x;
  const int w = t >> 6, l = t & 63, quad = l >> 4, lc = l & 15;
  const int ecol = (l & 7) * 8;
  const bf16* gE = Big + ((long)h * 256 + w * 64 + (l >> 3)) * 4096 + nbase + ecol;
  const int sn = t >> 3, sq = t & 7;
  const bf16* gK = src + (long)(b * 4096 + nbase + sn) * 512 + h * 64 + sq * 8;
  floatx4 acc[4][4] = {};
  for (int ks = 0; ks < 16; ++ks) {
    bf16x8 kv0 = *(const bf16x8*)(gK + (long)(ks * 64) * 512);
    bf16x8 kv1 = *(const bf16x8*)(gK + (long)(ks * 64 + 32) * 512);
    __syncthreads();   // previous iteration's LDS reads complete
#pragma unroll
    for (int i = 0; i < 8; ++i)
      async_copy16(gE + ks * 64 + (long)i * 8 * 4096, &Eb[w * 64 + i * 8][0]);
#pragma unroll
    for (int jj = 0; jj < 8; ++jj) Kt[sq * 8 + jj][sn ^ (sq * 8)] = kv0[jj];
#pragma unroll
    for (int jj = 0; jj < 8; ++jj) Kt[sq * 8 + jj][(32 + sn) ^ (sq * 8)] = kv1[jj];
    __syncthreads();
#pragma unroll
    for (int kk = 0; kk < 64; kk += 32) {
      bf16x8 af[4], bfr[4];
      if (z == 0) {
#pragma unroll
        for (int mt = 0; mt < 4; ++mt)
          af[mt] = *(const bf16x8*)&Eb[w * 64 + mt * 16 + lc][kk + quad * 8];
#pragma unroll
        for (int nt = 0; nt < 4; ++nt) {
          int d = nt * 16 + lc;
          bfr[nt] = *(const bf16x8*)&Kt[d][(kk + quad * 8) ^ ((d >> 3) << 3)];
        }
      } else {
#pragma unroll
        for (int mt = 0; mt < 4; ++mt) {
          int d = mt * 16 + lc;
          af[mt] = *(const bf16x8*)&Kt[d][(kk + quad * 8) ^ ((d >> 3) << 3)];
        }
#pragma unroll
        for (int nt = 0; nt < 4; ++nt)
          bfr[nt] = *(const bf16x8*)&Eb[w * 64 + nt * 16 + lc][kk + quad * 8];
      }
#pragma unroll
      for (int mt = 0; mt < 4; ++mt)
#pragma unroll
        for (int nt = 0; nt < 4; ++nt)
          acc[mt][nt] = MFMA16(af[mt], bfr[nt], acc[mt][nt]);
    }
  }
  bf16* obase = out + ((long)blockIdx.x * 64 + bh) * 16384;
  if (z == 0) {
#pragma unroll
    for (int mt = 0; mt < 4; ++mt)
#pragma unroll
      for (int nt = 0; nt < 4; ++nt)
#pragma unroll
        for (int i = 0; i < 4; ++i) {
          int r = w * 64 + mt * 16 + quad * 4 + i, d = nt * 16 + lc;
          obase[(long)r * 64 + d] = f2bf(acc[mt][nt][i]);
        }
  } else {
#pragma unroll
    for (int mt = 0; mt < 4; ++mt)
#pragma unroll
      for (int nt = 0; nt < 4; ++nt)
#pragma unroll
        for (int i = 0; i < 4; ++i) {
          int d = mt * 16 + quad * 4 + i, r = w * 64 + nt * 16 + lc;
          obase[(long)d * 256 + r] = f2bf(acc[mt][nt][i]);
        }
  }
}

// ---------------------------------------------------------------------------
// Attention, with partial-reduce fused into LDS staging (sums the 4 proj
// n-chunk partials, fp32 accum then one bf16 round — same numerics as the
// old reduce kernel). Per (b,h,128 rows): S=q*kp^T/8; softmax R=256; O=P*vp.
// ---------------------------------------------------------------------------
__global__ __launch_bounds__(512) void attn_kernel(
    const bf16* __restrict__ qb, const bf16* __restrict__ kp_part,
    const bf16* __restrict__ vp_part, bf16* __restrict__ ao) {
  const int bx = blockIdx.x, h = blockIdx.y, b = blockIdx.z;
  const int bh = b * 8 + h;
  __shared__ __align__(16) char smem_u[36864];   // kpl 256x72 / vtl 64x264 union
  __shared__ bf16 Pc[2][128][40];
  bf16(*kpl)[72] = (bf16(*)[72])smem_u;
  bf16(*vtl)[264] = (bf16(*)[264])smem_u;
  const int t = threadIdx.x;
  const int w = t >> 6, l = t & 63, quad = l >> 4, lc = l & 15;

  {  // stage kp = sum of 4 partials (256x64 bf16)
    const bf16* p = kp_part + (long)bh * 16384;
#pragma unroll
    for (int j = 0; j < 4; ++j) {
      long e = (long)(j * 512 + t) * 8;
      bf16x8 a = *(const bf16x8*)(p + e);
      bf16x8 bb = *(const bf16x8*)(p + 1048576 + e);
      bf16x8 c = *(const bf16x8*)(p + 2097152 + e);
      bf16x8 d = *(const bf16x8*)(p + 3145728 + e);
      bf16x8 o;
#pragma unroll
      for (int jj = 0; jj < 8; ++jj)
        o[jj] = f2bf(bf2f(a[jj]) + bf2f(bb[jj]) + bf2f(c[jj]) + bf2f(d[jj]));
      int e32 = j * 512 + t;
      *(bf16x8*)&kpl[e32 >> 3][(e32 & 7) * 8] = o;
    }
  }
  __syncthreads();

  // GEMM-1: scores; q A-frags direct from global.
  const long qrow = (long)(b * 4096 + bx * 128 + w * 16 + lc) * 512 + h * 64;
  floatx4 acc[16] = {};
#pragma unroll
  for (int kk = 0; kk < 64; kk += 32) {
    bf16x8 a = *(const bf16x8*)(qb + qrow + kk + quad * 8);
#pragma unroll
    for (int nt = 0; nt < 16; ++nt) {
      bf16x8 bfr = *(const bf16x8*)&kpl[nt * 16 + lc][kk + quad * 8];
      acc[nt] = MFMA16(a, bfr, acc[nt]);
    }
  }
  __syncthreads();   // kpl reads done; union becomes vtl

  {  // stage vpT = sum of 4 partials (64x256 bf16)
    const bf16* p = vp_part + (long)bh * 16384;
#pragma unroll
    for (int j = 0; j < 4; ++j) {
      long e = (long)(j * 512 + t) * 8;
      bf16x8 a = *(const bf16x8*)(p + e);
      bf16x8 bb = *(const bf16x8*)(p + 1048576 + e);
      bf16x8 c = *(const bf16x8*)(p + 2097152 + e);
      bf16x8 d = *(const bf16x8*)(p + 3145728 + e);
      bf16x8 o;
#pragma unroll
      for (int jj = 0; jj < 8; ++jj)
        o[jj] = f2bf(bf2f(a[jj]) + bf2f(bb[jj]) + bf2f(c[jj]) + bf2f(d[jj]));
      int e32 = j * 512 + t;
      *(bf16x8*)&vtl[e32 >> 5][(e32 & 31) * 8] = o;
    }
  }

  // softmax (C-layout: lane (quad,lc) holds rows quad*4+i, cols lc+16*nt)
  float mx[4] = {-1e30f, -1e30f, -1e30f, -1e30f};
#pragma unroll
  for (int nt = 0; nt < 16; ++nt)
#pragma unroll
    for (int i = 0; i < 4; ++i) {
      acc[nt][i] *= 0.125f;   // 1/sqrt(64)
      mx[i] = fmaxf(mx[i], acc[nt][i]);
    }
#pragma unroll
  for (int m = 1; m <= 8; m <<= 1)
#pragma unroll
    for (int i = 0; i < 4; ++i) mx[i] = fmaxf(mx[i], __shfl_xor(mx[i], m, 64));
  float sm[4] = {0.f, 0.f, 0.f, 0.f};
#pragma unroll
  for (int nt = 0; nt < 16; ++nt)
#pragma unroll
    for (int i = 0; i < 4; ++i) {
      float pp = __expf(acc[nt][i] - mx[i]);
      acc[nt][i] = pp;
      sm[i] += pp;
    }
#pragma unroll
  for (int m = 1; m <= 8; m <<= 1)
#pragma unroll
    for (int i = 0; i < 4; ++i) sm[i] += __shfl_xor(sm[i], m, 64);
  float inv[4];
#pragma unroll
  for (int i = 0; i < 4; ++i) inv[i] = 1.0f / sm[i];

  // GEMM-2: O = P*vp; P chunks (32 r) double-buffered, 1 barrier per chunk.
  floatx4 acc2[4] = {};
  for (int rs = 0; rs < 8; ++rs) {
    const int buf = rs & 1;
#pragma unroll
    for (int u = 0; u < 2; ++u) {
      int nt = rs * 2 + u;
#pragma unroll
      for (int i = 0; i < 4; ++i)
        Pc[buf][w * 16 + quad * 4 + i][u * 16 + lc] = f2bf(acc[nt][i] * inv[i]);
    }
    __syncthreads();   // also covers vtl staging on rs==0
    bf16x8 a2 = *(const bf16x8*)&Pc[buf][w * 16 + lc][quad * 8];
#pragma unroll
    for (int nt = 0; nt < 4; ++nt) {
      bf16x8 b2 = *(const bf16x8*)&vtl[nt * 16 + lc][rs * 32 + quad * 8];
      acc2[nt] = MFMA16(a2, b2, acc2[nt]);
    }
  }

#pragma unroll
  for (int nt = 0; nt < 4; ++nt)
#pragma unroll
    for (int i = 0; i < 4; ++i) {
      int row = bx * 128 + w * 16 + quad * 4 + i;
      int d = nt * 16 + lc;
      ao[(long)(b * 4096 + row) * 512 + h * 64 + d] = f2bf(acc2[nt][i]);
    }
}

// ---------------------------------------------------------------------------
extern "C" void kernel_launch(void* const* d_in, const int* in_sizes, int n_in,
                              void* d_out, int out_size, void* d_ws, size_t ws_size,
                              hipStream_t stream) {
  const float* x  = (const float*)d_in[0];
  const float* wq = (const float*)d_in[1];
  const float* wk = (const float*)d_in[2];
  const float* wv = (const float*)d_in[3];
  const float* E  = (const float*)d_in[4];
  const float* F  = (const float*)d_in[5];
  const float* wd = (const float*)d_in[6];
  const float* bd = (const float*)d_in[7];
  float* out = (float*)d_out;

  // workspace layout (bytes); total 186,646,528
  char* ws = (char*)d_ws;
  bf16* x_bf    = (bf16*)(ws + 0);            // 33,554,432 (dead after QKV -> attn_o)
  bf16* q_bf    = (bf16*)(ws + 33554432l);    // 33,554,432
  bf16* k_bf    = (bf16*)(ws + 67108864l);    // 33,554,432
  bf16* v_bf    = (bf16*)(ws + 100663296l);   // 33,554,432
  bf16* Et_g    = (bf16*)(ws + 134217728l);   // 16,777,216  (H,R,N)
  bf16* Ft_g    = (bf16*)(ws + 150994944l);   // 16,777,216
  bf16* Wt      = (bf16*)(ws + 167772160l);   //  1,572,864  [wq^T|wk^T|wv^T] (n,k)
  bf16* wdT     = (bf16*)(ws + 169345024l);   //    524,288
  bf16* kp_part = (bf16*)(ws + 169869312l);   //  8,388,608  [4][bh][r][d]
  bf16* vp_part = (bf16*)(ws + 178257920l);   //  8,388,608  [4][bh][d][r]
  bf16* attn_o  = x_bf;

  static bool attr_done = false;
  if (!attr_done) {
    hipFuncSetAttribute((const void*)gemm256_kernel<0>,
                        hipFuncAttributeMaxDynamicSharedMemorySize, 131072);
    hipFuncSetAttribute((const void*)gemm256_kernel<1>,
                        hipFuncAttributeMaxDynamicSharedMemorySize, 131072);
    attr_done = true;
  }

  dim3 tb(32, 8);
  cvt_bf16_kernel<<<8192, 256, 0, stream>>>(x, x_bf);
  transpose_w4_kernel<<<dim3(16, 16, 4), tb, 0, stream>>>(wq, wk, wv, wd, Wt, wdT);
  transpose_ef_kernel<<<dim3(128, 8, 16), tb, 0, stream>>>(E, F, Et_g, Ft_g);

  gemm256_kernel<0><<<768, 512, 131072, stream>>>(x_bf, Wt, q_bf, k_bf, v_bf, nullptr, nullptr);
  proj_kernel<<<dim3(4, 64, 2), 256, 0, stream>>>(Et_g, Ft_g, k_bf, v_bf, kp_part, vp_part);
  attn_kernel<<<dim3(32, 8, 8), 512, 0, stream>>>(q_bf, kp_part, vp_part, attn_o);
  gemm256_kernel<1><<<256, 512, 131072, stream>>>(attn_o, wdT, nullptr, nullptr, nullptr, out, bd);
}

// Round 2
// 364.847 us; speedup vs baseline: 1.0672x; 1.0458x over previous
//
#include <hip/hip_runtime.h>

// ClusteredLinformerAttention — round 5: de-VALU the attention kernel.
// (1) partial-reduce hoisted to a dedicated bandwidth kernel (was re-done
//     32x per (b,h) inside attn), (2) T14 issue-early vp staging, (3) deferred
//     softmax normalization (scale after PV), (4) exp2-domain softmax.
// B=8 N=4096 D=512 H=8 R=256 DEPTH=64.
// MFMA v_mfma_f32_16x16x32_bf16; layouts (m89/m120):
//   A[m=lane&15][k=quad*8+j], B[k=quad*8+j][n=lane&15], C/D: col=lane&15, row=quad*4+reg.

typedef __bf16 bf16;
typedef __attribute__((ext_vector_type(8))) __bf16 bf16x8;
typedef __attribute__((ext_vector_type(8))) unsigned short ushort8;
typedef __attribute__((ext_vector_type(4))) float floatx4;

#define MFMA16(a, b, c) __builtin_amdgcn_mfma_f32_16x16x32_bf16((a), (b), (c), 0, 0, 0)

static __device__ __forceinline__ unsigned short bf_bits(float f) {
  unsigned u = __builtin_bit_cast(unsigned, f);
  u += 0x7fffu + ((u >> 16) & 1u);   // RNE
  return (unsigned short)(u >> 16);
}
static __device__ __forceinline__ bf16 f2bf(float f) {
  unsigned short s = bf_bits(f);
  return __builtin_bit_cast(bf16, s);
}
static __device__ __forceinline__ float bf2f(bf16 v) {
  unsigned u = (unsigned)__builtin_bit_cast(unsigned short, v) << 16;
  return __builtin_bit_cast(float, u);
}
// async global->LDS, 16B/lane; LDS dest = wave-uniform base + lane*16.
static __device__ __forceinline__ void async_copy16(const void* g, void* l) {
  __builtin_amdgcn_global_load_lds((const __attribute__((address_space(1))) void*)g,
                                   (__attribute__((address_space(3))) void*)l, 16, 0, 0);
}

// ---------------------------------------------------------------------------
// fp32 -> bf16 bulk convert (x). 8 elems/thread.
// ---------------------------------------------------------------------------
__global__ void cvt_bf16_kernel(const float* __restrict__ src, bf16* __restrict__ dst) {
  long i = ((long)blockIdx.x * 256 + threadIdx.x) * 8;
  float4 a = *(const float4*)(src + i);
  float4 b = *(const float4*)(src + i + 4);
  ushort8 o;
  o[0] = bf_bits(a.x); o[1] = bf_bits(a.y); o[2] = bf_bits(a.z); o[3] = bf_bits(a.w);
  o[4] = bf_bits(b.x); o[5] = bf_bits(b.y); o[6] = bf_bits(b.z); o[7] = bf_bits(b.w);
  *(ushort8*)(dst + i) = o;
}

// ---------------------------------------------------------------------------
// Batched weight transpose: z selects (src,dst). dst[n*512+k] = bf16(src[k*512+n]).
// ---------------------------------------------------------------------------
__global__ void transpose_w4_kernel(const float* __restrict__ wq, const float* __restrict__ wk,
                                    const float* __restrict__ wv, const float* __restrict__ wd,
                                    bf16* __restrict__ Wt, bf16* __restrict__ wdT) {
  const int z = blockIdx.z;
  const float* src = z == 0 ? wq : (z == 1 ? wk : (z == 2 ? wv : wd));
  bf16* dst = z < 3 ? Wt + (long)z * 262144 : wdT;
  __shared__ float tile[32][33];
  const int k0 = blockIdx.x * 32, n0 = blockIdx.y * 32;
  const int tx = threadIdx.x, ty = threadIdx.y;   // (32, 8)
#pragma unroll
  for (int i = ty; i < 32; i += 8)
    tile[i][tx] = src[(long)(k0 + i) * 512 + n0 + tx];
  __syncthreads();
#pragma unroll
  for (int i = ty; i < 32; i += 8)
    dst[(long)(n0 + i) * 512 + k0 + tx] = f2bf(tile[tx][i]);
}

// ---------------------------------------------------------------------------
// E/F transpose, z = tensor*8 + head: dst[(h,r),n] = bf16(src[h,n,r]).
// ---------------------------------------------------------------------------
__global__ void transpose_ef_kernel(const float* __restrict__ E, const float* __restrict__ F,
                                    bf16* __restrict__ Et, bf16* __restrict__ Ft) {
  const int z = blockIdx.z, h = z & 7;
  const float* src = (z < 8 ? E : F) + (long)h * 4096 * 256;
  bf16* dst = (z < 8 ? Et : Ft) + (long)h * 256 * 4096;
  __shared__ float tile[32][33];
  const int k0 = blockIdx.x * 32, n0 = blockIdx.y * 32;   // k0: n-dim(4096), n0: r-dim(256)
  const int tx = threadIdx.x, ty = threadIdx.y;
#pragma unroll
  for (int i = ty; i < 32; i += 8)
    tile[i][tx] = src[(long)(k0 + i) * 256 + n0 + tx];
  __syncthreads();
#pragma unroll
  for (int i = ty; i < 32; i += 8)
    dst[(long)(n0 + i) * 4096 + k0 + tx] = f2bf(tile[tx][i]);
}

// ---------------------------------------------------------------------------
// 256x256 GEMM, K=512, C = A(M,512)*Bt(N,512)^T — counted-vmcnt deep pipeline.
// 8 waves (2M x 4N), per-wave 128x64 output (acc[8][4] f32x4 = 128 VGPR).
// K split into 16 sub-tiles of BK=32; 4-slot LDS ring buffer (A and B each
// [4][256][32] bf16 = 64 KiB; 128 KiB dynamic LDS total), prefetch distance 3.
// Per sub-tile: 12 ds_read_b128 + 32 MFMA + 4 global_load_lds, ONE raw
// s_barrier with s_waitcnt vmcnt(8) (counted, never 0 until tail).
// LDS chunk-swizzle: 16B slot c' = c ^ ((row>>1)&3) applied on BOTH sides:
// pre-swizzled global source (gload_lds dest stays linear, m104/m231) and the
// ds_read address -> 2-way (free) bank access on the stride-64B rows.
// XCD swizzle: p = lin&7 owns a contiguous m-band; A-rows stay hot in its L2.
// MODE 0: N=1536 (NB=6), split-write q/k/v bf16. MODE 1: N=512 (NB=2), fp32+bias.
// ---------------------------------------------------------------------------
template <int MODE>
__global__ __launch_bounds__(512, 2) void gemm256_kernel(
    const bf16* __restrict__ A, const bf16* __restrict__ Bt,
    bf16* __restrict__ oq, bf16* __restrict__ ok, bf16* __restrict__ ov,
    float* __restrict__ of, const float* __restrict__ bias) {
  constexpr int NBt = MODE == 0 ? 6 : 2;
  extern __shared__ __align__(16) char smem[];   // [A:65536][B:65536]
  const int lin = blockIdx.x;
  const int p = lin & 7, q = lin >> 3;
  const int m0 = (p * 16 + q / NBt) * 256, n0 = (q % NBt) * 256;
  const int t = threadIdx.x;
  const int w = t >> 6, l = t & 63, quad = l >> 4, lc = l & 15;
  const int wr = w >> 2, wc = w & 3;   // 2 (M) x 4 (N)

  // --- staging addressing: wave w stages rows [j*128 + w*16, +16) per instr.
  // LDS linear (row, c=lane&3); source chunk pre-swizzled: q = c ^ ((row>>1)&3)
  // = (l&3) ^ ((l>>3)&3) since w*16, j*128 are 0 mod 16.
  const int srow = w * 16 + (l >> 2);
  const int sq = (l & 3) ^ ((l >> 3) & 3);
  const bf16* gA0 = A + (long)(m0 + srow) * 512 + sq * 8;
  const bf16* gB0 = Bt + (long)(n0 + srow) * 512 + sq * 8;
  bf16* AsW = (bf16*)smem + w * 512;             // + buf*8192 + j*4096 (elems)
  bf16* BsW = (bf16*)(smem + 65536) + w * 512;

  // --- read addressing (bytes within a buffer): row*64 + swizzled 16B slot.
  // frag row = {wr*128|wc*64} + mt*16 + lc  ->  (row>>1)&3 == (lc>>1)&3.
  const int swz = (quad ^ ((lc >> 1) & 3)) << 4;
  const int a_rd = (wr * 128 + lc) * 64 + swz;
  const int b_rd = (wc * 64 + lc) * 64 + swz;

  floatx4 acc[8][4] = {};

#define STAGE_A(s_, buf_)                                              \
  do {                                                                 \
    async_copy16(gA0 + (s_) * 32, AsW + (buf_) * 8192);                \
    async_copy16(gA0 + 65536l + (s_) * 32, AsW + (buf_) * 8192 + 4096);\
  } while (0)
#define STAGE_B(s_, buf_)                                              \
  do {                                                                 \
    async_copy16(gB0 + (s_) * 32, BsW + (buf_) * 8192);                \
    async_copy16(gB0 + 65536l + (s_) * 32, BsW + (buf_) * 8192 + 4096);\
  } while (0)

  // prologue: stage sub-tiles 0,1,2 (4 loads/wave each)
  STAGE_A(0, 0); STAGE_B(0, 0);
  STAGE_A(1, 1); STAGE_B(1, 1);
  STAGE_A(2, 2); STAGE_B(2, 2);
  asm volatile("s_waitcnt vmcnt(8)" ::: "memory");   // sub-tile 0 landed (mine)
  __builtin_amdgcn_sched_barrier(0);
  __builtin_amdgcn_s_barrier();                      // everyone's sub-tile 0
  __builtin_amdgcn_sched_barrier(0);

#pragma unroll
  for (int s = 0; s < 16; ++s) {
    const int buf = s & 3, tb = (s + 3) & 3;   // tb == (s-1)&3: its reads are done
    const char* Ab = smem + buf * 16384;
    const char* Bb = smem + 65536 + buf * 16384;
    bf16x8 af[4], bfr[4];
    // phase A: B frags (all nt) + A frags mt 0..3; issue A staging for s+3
#pragma unroll
    for (int nt = 0; nt < 4; ++nt)
      bfr[nt] = *(const bf16x8*)(Bb + b_rd + nt * 1024);
#pragma unroll
    for (int mt = 0; mt < 4; ++mt)
      af[mt] = *(const bf16x8*)(Ab + a_rd + mt * 1024);
    if (s < 13) STAGE_A(s + 3, tb);
    __builtin_amdgcn_s_setprio(1);
#pragma unroll
    for (int mt = 0; mt < 4; ++mt)
#pragma unroll
      for (int nt = 0; nt < 4; ++nt)
        acc[mt][nt] = MFMA16(af[mt], bfr[nt], acc[mt][nt]);
    __builtin_amdgcn_s_setprio(0);
    // phase B: A frags mt 4..7 (B frags reused); issue B staging for s+3
#pragma unroll
    for (int mt = 0; mt < 4; ++mt)
      af[mt] = *(const bf16x8*)(Ab + a_rd + (mt + 4) * 1024);
    if (s < 13) STAGE_B(s + 3, tb);
    __builtin_amdgcn_s_setprio(1);
#pragma unroll
    for (int mt = 0; mt < 4; ++mt)
#pragma unroll
      for (int nt = 0; nt < 4; ++nt)
        acc[mt + 4][nt] = MFMA16(af[mt], bfr[nt], acc[mt + 4][nt]);
    __builtin_amdgcn_s_setprio(0);
    // boundary: ensure staging(s+1) landed everywhere. Counted wait:
    // in flight after staging(s+1) = sub-tiles s+2,s+3 = 8 loads (tail: 4/0).
    if (s < 15) {
      if (s <= 12)      { asm volatile("s_waitcnt vmcnt(8)" ::: "memory"); }
      else if (s == 13) { asm volatile("s_waitcnt vmcnt(4)" ::: "memory"); }
      else              { asm volatile("s_waitcnt vmcnt(0)" ::: "memory"); }
      __builtin_amdgcn_sched_barrier(0);
      __builtin_amdgcn_s_barrier();
      __builtin_amdgcn_sched_barrier(0);
    }
  }
#undef STAGE_A
#undef STAGE_B

  if (MODE == 0) {
    const int which = n0 >> 9, nb = n0 & 511;
    bf16* dst = which == 0 ? oq : (which == 1 ? ok : ov);
#pragma unroll
    for (int mt = 0; mt < 8; ++mt)
#pragma unroll
      for (int nt = 0; nt < 4; ++nt)
#pragma unroll
        for (int i = 0; i < 4; ++i) {
          int row = m0 + wr * 128 + mt * 16 + quad * 4 + i;
          int col = nb + wc * 64 + nt * 16 + lc;
          dst[(long)row * 512 + col] = f2bf(acc[mt][nt][i]);
        }
  } else {
#pragma unroll
    for (int mt = 0; mt < 8; ++mt)
#pragma unroll
      for (int nt = 0; nt < 4; ++nt)
#pragma unroll
        for (int i = 0; i < 4; ++i) {
          int row = m0 + wr * 128 + mt * 16 + quad * 4 + i;
          int col = n0 + wc * 64 + nt * 16 + lc;
          of[(long)row * 512 + col] = acc[mt][nt][i] + bias[col];
        }
  }
}

// ---------------------------------------------------------------------------
// Projection (atomic-free, 4 n-chunk bf16 partials):
//  z=0: kp_part[nc][bh][r][d] = sum_n k[b,n,h,d] * E[h,n,r]
//  z=1: vp_part[nc][bh][d][r] = sum_n v[b,n,h,d] * F[h,n,r]
// Big side (E/F^T, 256 x k) via global_load_lds; small side (K/V) LDS-
// transposed with XOR swizzle (2-way max on store & read).
// ---------------------------------------------------------------------------
__global__ __launch_bounds__(256) void proj_kernel(
    const bf16* __restrict__ Et_g, const bf16* __restrict__ Ft_g,
    const bf16* __restrict__ kb, const bf16* __restrict__ vb,
    bf16* __restrict__ kp_part, bf16* __restrict__ vp_part) {
  const int z = blockIdx.z;
  const bf16* Big = z ? Ft_g : Et_g;
  const bf16* src = z ? vb : kb;
  bf16* out = z ? vp_part : kp_part;
  const int bh = blockIdx.y, b = bh >> 3, h = bh & 7;
  const int nbase = blockIdx.x * 1024;
  __shared__ bf16 Eb[256][64];
  __shared__ bf16 Kt[64][72];
  const int t = threadIdx.x;
  const int w = t >> 6, l = t & 63, quad = l >> 4, lc = l & 15;
  const int ecol = (l & 7) * 8;
  const bf16* gE = Big + ((long)h * 256 + w * 64 + (l >> 3)) * 4096 + nbase + ecol;
  const int sn = t >> 3, sq = t & 7;
  const bf16* gK = src + (long)(b * 4096 + nbase + sn) * 512 + h * 64 + sq * 8;
  floatx4 acc[4][4] = {};
  for (int ks = 0; ks < 16; ++ks) {
    bf16x8 kv0 = *(const bf16x8*)(gK + (long)(ks * 64) * 512);
    bf16x8 kv1 = *(const bf16x8*)(gK + (long)(ks * 64 + 32) * 512);
    __syncthreads();   // previous iteration's LDS reads complete
#pragma unroll
    for (int i = 0; i < 8; ++i)
      async_copy16(gE + ks * 64 + (long)i * 8 * 4096, &Eb[w * 64 + i * 8][0]);
#pragma unroll
    for (int jj = 0; jj < 8; ++jj) Kt[sq * 8 + jj][sn ^ (sq * 8)] = kv0[jj];
#pragma unroll
    for (int jj = 0; jj < 8; ++jj) Kt[sq * 8 + jj][(32 + sn) ^ (sq * 8)] = kv1[jj];
    __syncthreads();
#pragma unroll
    for (int kk = 0; kk < 64; kk += 32) {
      bf16x8 af[4], bfr[4];
      if (z == 0) {
#pragma unroll
        for (int mt = 0; mt < 4; ++mt)
          af[mt] = *(const bf16x8*)&Eb[w * 64 + mt * 16 + lc][kk + quad * 8];
#pragma unroll
        for (int nt = 0; nt < 4; ++nt) {
          int d = nt * 16 + lc;
          bfr[nt] = *(const bf16x8*)&Kt[d][(kk + quad * 8) ^ ((d >> 3) << 3)];
        }
      } else {
#pragma unroll
        for (int mt = 0; mt < 4; ++mt) {
          int d = mt * 16 + lc;
          af[mt] = *(const bf16x8*)&Kt[d][(kk + quad * 8) ^ ((d >> 3) << 3)];
        }
#pragma unroll
        for (int nt = 0; nt < 4; ++nt)
          bfr[nt] = *(const bf16x8*)&Eb[w * 64 + nt * 16 + lc][kk + quad * 8];
      }
#pragma unroll
      for (int mt = 0; mt < 4; ++mt)
#pragma unroll
        for (int nt = 0; nt < 4; ++nt)
          acc[mt][nt] = MFMA16(af[mt], bfr[nt], acc[mt][nt]);
    }
  }
  bf16* obase = out + ((long)blockIdx.x * 64 + bh) * 16384;
  if (z == 0) {
#pragma unroll
    for (int mt = 0; mt < 4; ++mt)
#pragma unroll
      for (int nt = 0; nt < 4; ++nt)
#pragma unroll
        for (int i = 0; i < 4; ++i) {
          int r = w * 64 + mt * 16 + quad * 4 + i, d = nt * 16 + lc;
          obase[(long)r * 64 + d] = f2bf(acc[mt][nt][i]);
        }
  } else {
#pragma unroll
    for (int mt = 0; mt < 4; ++mt)
#pragma unroll
      for (int nt = 0; nt < 4; ++nt)
#pragma unroll
        for (int i = 0; i < 4; ++i) {
          int d = mt * 16 + quad * 4 + i, r = w * 64 + nt * 16 + lc;
          obase[(long)d * 256 + r] = f2bf(acc[mt][nt][i]);
        }
  }
}

// ---------------------------------------------------------------------------
// Partial reduce: kp/vp = sum of 4 proj n-chunk partials. fp32 accum, one
// bf16 round — numerics identical to the old fused staging. Pure-BW kernel.
// z=0: kp_part -> kp (1,048,576 elems); z=1: vp_part -> vp.
// ---------------------------------------------------------------------------
__global__ void reduce_parts_kernel(const bf16* __restrict__ kp_part,
                                    const bf16* __restrict__ vp_part,
                                    bf16* __restrict__ kp, bf16* __restrict__ vp) {
  const bf16* src = blockIdx.z ? vp_part : kp_part;
  bf16* dst = blockIdx.z ? vp : kp;
  long i = ((long)blockIdx.x * 256 + threadIdx.x) * 8;
  bf16x8 a = *(const bf16x8*)(src + i);
  bf16x8 b = *(const bf16x8*)(src + 1048576 + i);
  bf16x8 c = *(const bf16x8*)(src + 2097152 + i);
  bf16x8 d = *(const bf16x8*)(src + 3145728 + i);
  bf16x8 o;
#pragma unroll
  for (int j = 0; j < 8; ++j)
    o[j] = f2bf(bf2f(a[j]) + bf2f(b[j]) + bf2f(c[j]) + bf2f(d[j]));
  *(bf16x8*)(dst + i) = o;
}

// ---------------------------------------------------------------------------
// Attention. Per (b,h,128 rows): S=q*kp^T (exp2-domain softmax, R=256);
// O=P_unnorm*vp, row-scaled by 1/sum afterwards. kp/vp pre-summed by
// reduce_parts_kernel; staging is a pure vector copy with T14 issue-early
// vp loads held in registers across GEMM-1.
// ---------------------------------------------------------------------------
__global__ __launch_bounds__(512) void attn_kernel(
    const bf16* __restrict__ qb, const bf16* __restrict__ kp,
    const bf16* __restrict__ vp, bf16* __restrict__ ao) {
  const int bx = blockIdx.x, h = blockIdx.y, b = blockIdx.z;
  const int bh = b * 8 + h;
  __shared__ __align__(16) char smem_u[36864];   // kpl 256x72 / vtl 64x264 union
  __shared__ bf16 Pc[2][128][40];
  bf16(*kpl)[72] = (bf16(*)[72])smem_u;
  bf16(*vtl)[264] = (bf16(*)[264])smem_u;
  const int t = threadIdx.x;
  const int w = t >> 6, l = t & 63, quad = l >> 4, lc = l & 15;

  // T14: issue vp loads now (held in regs across GEMM-1), stage kp to LDS.
  const bf16* pk = kp + (long)bh * 16384;
  const bf16* pv = vp + (long)bh * 16384;
  bf16x8 vreg[4];
#pragma unroll
  for (int j = 0; j < 4; ++j)
    vreg[j] = *(const bf16x8*)(pv + (long)(j * 512 + t) * 8);
#pragma unroll
  for (int j = 0; j < 4; ++j) {
    int e32 = j * 512 + t;
    *(bf16x8*)&kpl[e32 >> 3][(e32 & 7) * 8] = *(const bf16x8*)(pk + (long)e32 * 8);
  }
  __syncthreads();

  // GEMM-1: scores; q A-frags direct from global.
  const long qrow = (long)(b * 4096 + bx * 128 + w * 16 + lc) * 512 + h * 64;
  floatx4 acc[16] = {};
#pragma unroll
  for (int kk = 0; kk < 64; kk += 32) {
    bf16x8 a = *(const bf16x8*)(qb + qrow + kk + quad * 8);
#pragma unroll
    for (int nt = 0; nt < 16; ++nt) {
      bf16x8 bfr = *(const bf16x8*)&kpl[nt * 16 + lc][kk + quad * 8];
      acc[nt] = MFMA16(a, bfr, acc[nt]);
    }
  }
  __syncthreads();   // kpl reads done; union becomes vtl

  {  // write vp tile (64x256 bf16) from the pre-issued registers
#pragma unroll
    for (int j = 0; j < 4; ++j) {
      int e32 = j * 512 + t;
      *(bf16x8*)&vtl[e32 >> 5][(e32 & 31) * 8] = vreg[j];
    }
  }

  // softmax in exp2 domain: scale = (1/8) * log2(e); P left unnormalized,
  // row 1/sum applied to acc2 after PV (commutes with the matmul).
  constexpr float SC = 0.18033688011112042f;
  float mx[4] = {-1e30f, -1e30f, -1e30f, -1e30f};
#pragma unroll
  for (int nt = 0; nt < 16; ++nt)
#pragma unroll
    for (int i = 0; i < 4; ++i) {
      acc[nt][i] *= SC;
      mx[i] = fmaxf(mx[i], acc[nt][i]);
    }
#pragma unroll
  for (int m = 1; m <= 8; m <<= 1)
#pragma unroll
    for (int i = 0; i < 4; ++i) mx[i] = fmaxf(mx[i], __shfl_xor(mx[i], m, 64));
  float sm[4] = {0.f, 0.f, 0.f, 0.f};
#pragma unroll
  for (int nt = 0; nt < 16; ++nt)
#pragma unroll
    for (int i = 0; i < 4; ++i) {
      float pp = __builtin_amdgcn_exp2f(acc[nt][i] - mx[i]);
      acc[nt][i] = pp;
      sm[i] += pp;
    }
#pragma unroll
  for (int m = 1; m <= 8; m <<= 1)
#pragma unroll
    for (int i = 0; i < 4; ++i) sm[i] += __shfl_xor(sm[i], m, 64);
  float inv[4];
#pragma unroll
  for (int i = 0; i < 4; ++i) inv[i] = 1.0f / sm[i];

  // GEMM-2: O = P*vp; P chunks (32 r) double-buffered, 1 barrier per chunk.
  floatx4 acc2[4] = {};
  for (int rs = 0; rs < 8; ++rs) {
    const int buf = rs & 1;
#pragma unroll
    for (int u = 0; u < 2; ++u) {
      int nt = rs * 2 + u;
#pragma unroll
      for (int i = 0; i < 4; ++i)
        Pc[buf][w * 16 + quad * 4 + i][u * 16 + lc] = f2bf(acc[nt][i]);
    }
    __syncthreads();   // also covers vtl staging on rs==0
    bf16x8 a2 = *(const bf16x8*)&Pc[buf][w * 16 + lc][quad * 8];
#pragma unroll
    for (int nt = 0; nt < 4; ++nt) {
      bf16x8 b2 = *(const bf16x8*)&vtl[nt * 16 + lc][rs * 32 + quad * 8];
      acc2[nt] = MFMA16(a2, b2, acc2[nt]);
    }
  }

#pragma unroll
  for (int nt = 0; nt < 4; ++nt)
#pragma unroll
    for (int i = 0; i < 4; ++i) {
      int row = bx * 128 + w * 16 + quad * 4 + i;
      int d = nt * 16 + lc;
      ao[(long)(b * 4096 + row) * 512 + h * 64 + d] = f2bf(acc2[nt][i] * inv[i]);
    }
}

// ---------------------------------------------------------------------------
extern "C" void kernel_launch(void* const* d_in, const int* in_sizes, int n_in,
                              void* d_out, int out_size, void* d_ws, size_t ws_size,
                              hipStream_t stream) {
  const float* x  = (const float*)d_in[0];
  const float* wq = (const float*)d_in[1];
  const float* wk = (const float*)d_in[2];
  const float* wv = (const float*)d_in[3];
  const float* E  = (const float*)d_in[4];
  const float* F  = (const float*)d_in[5];
  const float* wd = (const float*)d_in[6];
  const float* bd = (const float*)d_in[7];
  float* out = (float*)d_out;

  // workspace layout (bytes); total 186,646,528
  char* ws = (char*)d_ws;
  bf16* x_bf    = (bf16*)(ws + 0);            // 33,554,432 (dead after QKV -> attn_o)
  bf16* q_bf    = (bf16*)(ws + 33554432l);    // 33,554,432
  bf16* k_bf    = (bf16*)(ws + 67108864l);    // 33,554,432 (dead after proj -> kp/vp)
  bf16* v_bf    = (bf16*)(ws + 100663296l);   // 33,554,432
  bf16* Et_g    = (bf16*)(ws + 134217728l);   // 16,777,216  (H,R,N)
  bf16* Ft_g    = (bf16*)(ws + 150994944l);   // 16,777,216
  bf16* Wt      = (bf16*)(ws + 167772160l);   //  1,572,864  [wq^T|wk^T|wv^T] (n,k)
  bf16* wdT     = (bf16*)(ws + 169345024l);   //    524,288
  bf16* kp_part = (bf16*)(ws + 169869312l);   //  8,388,608  [4][bh][r][d]
  bf16* vp_part = (bf16*)(ws + 178257920l);   //  8,388,608  [4][bh][d][r]
  bf16* attn_o  = x_bf;
  bf16* kp_sum  = k_bf;                       //  2,097,152  (aliases dead k_bf)
  bf16* vp_sum  = (bf16*)(ws + 67108864l + 2097152l);

  static bool attr_done = false;
  if (!attr_done) {
    hipFuncSetAttribute((const void*)gemm256_kernel<0>,
                        hipFuncAttributeMaxDynamicSharedMemorySize, 131072);
    hipFuncSetAttribute((const void*)gemm256_kernel<1>,
                        hipFuncAttributeMaxDynamicSharedMemorySize, 131072);
    attr_done = true;
  }

  dim3 tb(32, 8);
  cvt_bf16_kernel<<<8192, 256, 0, stream>>>(x, x_bf);
  transpose_w4_kernel<<<dim3(16, 16, 4), tb, 0, stream>>>(wq, wk, wv, wd, Wt, wdT);
  transpose_ef_kernel<<<dim3(128, 8, 16), tb, 0, stream>>>(E, F, Et_g, Ft_g);

  gemm256_kernel<0><<<768, 512, 131072, stream>>>(x_bf, Wt, q_bf, k_bf, v_bf, nullptr, nullptr);
  proj_kernel<<<dim3(4, 64, 2), 256, 0, stream>>>(Et_g, Ft_g, k_bf, v_bf, kp_part, vp_part);
  reduce_parts_kernel<<<dim3(512, 1, 2), 256, 0, stream>>>(kp_part, vp_part, kp_sum, vp_sum);
  attn_kernel<<<dim3(32, 8, 8), 512, 0, stream>>>(q_bf, kp_sum, vp_sum, attn_o);
  gemm256_kernel<1><<<256, 512, 131072, stream>>>(attn_o, wdT, nullptr, nullptr, nullptr, out, bd);
}

// Round 3
// 349.460 us; speedup vs baseline: 1.1141x; 1.0440x over previous
//
#include <hip/hip_runtime.h>

// ClusteredLinformerAttention — round 6: m201-style dual-barrier phase
// structure in the 256x256 GEMM (reads+stage -> barrier -> MFMA burst ->
// barrier, setprio inside), on top of the round-5 ring-4 counted-vmcnt
// staging (unchanged bytes/addresses). Rest of the pipeline unchanged.
// B=8 N=4096 D=512 H=8 R=256 DEPTH=64.
// MFMA v_mfma_f32_16x16x32_bf16; layouts (m89/m120):
//   A[m=lane&15][k=quad*8+j], B[k=quad*8+j][n=lane&15], C/D: col=lane&15, row=quad*4+reg.

typedef __bf16 bf16;
typedef __attribute__((ext_vector_type(8))) __bf16 bf16x8;
typedef __attribute__((ext_vector_type(8))) unsigned short ushort8;
typedef __attribute__((ext_vector_type(4))) float floatx4;

#define MFMA16(a, b, c) __builtin_amdgcn_mfma_f32_16x16x32_bf16((a), (b), (c), 0, 0, 0)

static __device__ __forceinline__ unsigned short bf_bits(float f) {
  unsigned u = __builtin_bit_cast(unsigned, f);
  u += 0x7fffu + ((u >> 16) & 1u);   // RNE
  return (unsigned short)(u >> 16);
}
static __device__ __forceinline__ bf16 f2bf(float f) {
  unsigned short s = bf_bits(f);
  return __builtin_bit_cast(bf16, s);
}
static __device__ __forceinline__ float bf2f(bf16 v) {
  unsigned u = (unsigned)__builtin_bit_cast(unsigned short, v) << 16;
  return __builtin_bit_cast(float, u);
}
// async global->LDS, 16B/lane; LDS dest = wave-uniform base + lane*16.
static __device__ __forceinline__ void async_copy16(const void* g, void* l) {
  __builtin_amdgcn_global_load_lds((const __attribute__((address_space(1))) void*)g,
                                   (__attribute__((address_space(3))) void*)l, 16, 0, 0);
}

// ---------------------------------------------------------------------------
// fp32 -> bf16 bulk convert (x). 8 elems/thread.
// ---------------------------------------------------------------------------
__global__ void cvt_bf16_kernel(const float* __restrict__ src, bf16* __restrict__ dst) {
  long i = ((long)blockIdx.x * 256 + threadIdx.x) * 8;
  float4 a = *(const float4*)(src + i);
  float4 b = *(const float4*)(src + i + 4);
  ushort8 o;
  o[0] = bf_bits(a.x); o[1] = bf_bits(a.y); o[2] = bf_bits(a.z); o[3] = bf_bits(a.w);
  o[4] = bf_bits(b.x); o[5] = bf_bits(b.y); o[6] = bf_bits(b.z); o[7] = bf_bits(b.w);
  *(ushort8*)(dst + i) = o;
}

// ---------------------------------------------------------------------------
// Batched weight transpose: z selects (src,dst). dst[n*512+k] = bf16(src[k*512+n]).
// ---------------------------------------------------------------------------
__global__ void transpose_w4_kernel(const float* __restrict__ wq, const float* __restrict__ wk,
                                    const float* __restrict__ wv, const float* __restrict__ wd,
                                    bf16* __restrict__ Wt, bf16* __restrict__ wdT) {
  const int z = blockIdx.z;
  const float* src = z == 0 ? wq : (z == 1 ? wk : (z == 2 ? wv : wd));
  bf16* dst = z < 3 ? Wt + (long)z * 262144 : wdT;
  __shared__ float tile[32][33];
  const int k0 = blockIdx.x * 32, n0 = blockIdx.y * 32;
  const int tx = threadIdx.x, ty = threadIdx.y;   // (32, 8)
#pragma unroll
  for (int i = ty; i < 32; i += 8)
    tile[i][tx] = src[(long)(k0 + i) * 512 + n0 + tx];
  __syncthreads();
#pragma unroll
  for (int i = ty; i < 32; i += 8)
    dst[(long)(n0 + i) * 512 + k0 + tx] = f2bf(tile[tx][i]);
}

// ---------------------------------------------------------------------------
// E/F transpose, z = tensor*8 + head: dst[(h,r),n] = bf16(src[h,n,r]).
// ---------------------------------------------------------------------------
__global__ void transpose_ef_kernel(const float* __restrict__ E, const float* __restrict__ F,
                                    bf16* __restrict__ Et, bf16* __restrict__ Ft) {
  const int z = blockIdx.z, h = z & 7;
  const float* src = (z < 8 ? E : F) + (long)h * 4096 * 256;
  bf16* dst = (z < 8 ? Et : Ft) + (long)h * 256 * 4096;
  __shared__ float tile[32][33];
  const int k0 = blockIdx.x * 32, n0 = blockIdx.y * 32;   // k0: n-dim(4096), n0: r-dim(256)
  const int tx = threadIdx.x, ty = threadIdx.y;
#pragma unroll
  for (int i = ty; i < 32; i += 8)
    tile[i][tx] = src[(long)(k0 + i) * 256 + n0 + tx];
  __syncthreads();
#pragma unroll
  for (int i = ty; i < 32; i += 8)
    dst[(long)(n0 + i) * 4096 + k0 + tx] = f2bf(tile[tx][i]);
}

// ---------------------------------------------------------------------------
// 256x256 GEMM, K=512, C = A(M,512)*Bt(N,512)^T — counted-vmcnt ring pipeline
// with m201-style dual-barrier phases.
// 8 waves (2M x 4N), per-wave 128x64 output (acc[8][4] f32x4 = 128 VGPR).
// K split into 16 sub-tiles of BK=32; 4-slot LDS ring buffer, prefetch dist 3.
// Per sub-tile, TWO phases, each: {ds_reads for this cluster; 2 gload_lds} ->
// barrier -> setprio(1) 16 MFMA setprio(0) -> barrier. Counted vmcnt(8)
// (never 0 until tail) placed after MFMA-hi, before the barrier that opens
// the next sub-tile's reads.
// LDS chunk-swizzle: 16B slot c' = c ^ ((row>>1)&3) on BOTH sides (pre-
// swizzled global source, gload_lds dest linear — m104/m231; swizzled read).
// XCD swizzle: p = lin&7 owns a contiguous m-band (A hot in its L2).
// MODE 0: N=1536 (NB=6), split-write q/k/v bf16. MODE 1: N=512 (NB=2), fp32+bias.
// ---------------------------------------------------------------------------
template <int MODE>
__global__ __launch_bounds__(512, 2) void gemm256_kernel(
    const bf16* __restrict__ A, const bf16* __restrict__ Bt,
    bf16* __restrict__ oq, bf16* __restrict__ ok, bf16* __restrict__ ov,
    float* __restrict__ of, const float* __restrict__ bias) {
  constexpr int NBt = MODE == 0 ? 6 : 2;
  extern __shared__ __align__(16) char smem[];   // [A:65536][B:65536]
  const int lin = blockIdx.x;
  const int p = lin & 7, q = lin >> 3;
  const int m0 = (p * 16 + q / NBt) * 256, n0 = (q % NBt) * 256;
  const int t = threadIdx.x;
  const int w = t >> 6, l = t & 63, quad = l >> 4, lc = l & 15;
  const int wr = w >> 2, wc = w & 3;   // 2 (M) x 4 (N)

  // --- staging addressing: wave w stages rows [j*128 + w*16, +16) per instr.
  // LDS linear (row, c=lane&3); source chunk pre-swizzled: q = c ^ ((row>>1)&3)
  // = (l&3) ^ ((l>>3)&3) since w*16, j*128 are 0 mod 16.
  const int srow = w * 16 + (l >> 2);
  const int sq = (l & 3) ^ ((l >> 3) & 3);
  const bf16* gA0 = A + (long)(m0 + srow) * 512 + sq * 8;
  const bf16* gB0 = Bt + (long)(n0 + srow) * 512 + sq * 8;
  bf16* AsW = (bf16*)smem + w * 512;             // + buf*8192 + j*4096 (elems)
  bf16* BsW = (bf16*)(smem + 65536) + w * 512;

  // --- read addressing (bytes within a buffer): row*64 + swizzled 16B slot.
  // frag row = {wr*128|wc*64} + mt*16 + lc  ->  (row>>1)&3 == (lc>>1)&3.
  const int swz = (quad ^ ((lc >> 1) & 3)) << 4;
  const int a_rd = (wr * 128 + lc) * 64 + swz;
  const int b_rd = (wc * 64 + lc) * 64 + swz;

  floatx4 acc[8][4] = {};

#define STAGE_A(s_, buf_)                                              \
  do {                                                                 \
    async_copy16(gA0 + (s_) * 32, AsW + (buf_) * 8192);                \
    async_copy16(gA0 + 65536l + (s_) * 32, AsW + (buf_) * 8192 + 4096);\
  } while (0)
#define STAGE_B(s_, buf_)                                              \
  do {                                                                 \
    async_copy16(gB0 + (s_) * 32, BsW + (buf_) * 8192);                \
    async_copy16(gB0 + 65536l + (s_) * 32, BsW + (buf_) * 8192 + 4096);\
  } while (0)
#define SBAR()                                                         \
  do {                                                                 \
    __builtin_amdgcn_sched_barrier(0);                                 \
    __builtin_amdgcn_s_barrier();                                      \
    __builtin_amdgcn_sched_barrier(0);                                 \
  } while (0)

  // prologue: stage sub-tiles 0,1,2 (4 loads/wave each)
  STAGE_A(0, 0); STAGE_B(0, 0);
  STAGE_A(1, 1); STAGE_B(1, 1);
  STAGE_A(2, 2); STAGE_B(2, 2);
  asm volatile("s_waitcnt vmcnt(8)" ::: "memory");   // sub-tile 0 landed (mine)
  SBAR();

#pragma unroll
  for (int s = 0; s < 16; ++s) {
    const int buf = s & 3, tb = (s + 3) & 3;   // tb == (s-1)&3: its reads are done
    const char* Ab = smem + buf * 16384;
    const char* Bb = smem + 65536 + buf * 16384;
    bf16x8 af[4], af2[4], bfr[4];
    // ---- phase A: reads (B all nt + A lo), stage A(s+3); barrier; 16 MFMA
#pragma unroll
    for (int nt = 0; nt < 4; ++nt)
      bfr[nt] = *(const bf16x8*)(Bb + b_rd + nt * 1024);
#pragma unroll
    for (int mt = 0; mt < 4; ++mt)
      af[mt] = *(const bf16x8*)(Ab + a_rd + mt * 1024);
    if (s < 13) STAGE_A(s + 3, tb);
    SBAR();
    __builtin_amdgcn_s_setprio(1);
#pragma unroll
    for (int mt = 0; mt < 4; ++mt)
#pragma unroll
      for (int nt = 0; nt < 4; ++nt)
        acc[mt][nt] = MFMA16(af[mt], bfr[nt], acc[mt][nt]);
    __builtin_amdgcn_s_setprio(0);
    SBAR();
    // ---- phase B: reads (A hi), stage B(s+3); barrier; 16 MFMA
#pragma unroll
    for (int mt = 0; mt < 4; ++mt)
      af2[mt] = *(const bf16x8*)(Ab + a_rd + (mt + 4) * 1024);
    if (s < 13) STAGE_B(s + 3, tb);
    SBAR();
    __builtin_amdgcn_s_setprio(1);
#pragma unroll
    for (int mt = 0; mt < 4; ++mt)
#pragma unroll
      for (int nt = 0; nt < 4; ++nt)
        acc[mt + 4][nt] = MFMA16(af2[mt], bfr[nt], acc[mt + 4][nt]);
    __builtin_amdgcn_s_setprio(0);
    // boundary: ensure staging(s+1) landed before the barrier that opens
    // s+1's reads. In flight after staging(s+1)..(s+3): 8 loads (tail: 4/0).
    if (s < 15) {
      if (s <= 12)      { asm volatile("s_waitcnt vmcnt(8)" ::: "memory"); }
      else if (s == 13) { asm volatile("s_waitcnt vmcnt(4)" ::: "memory"); }
      else              { asm volatile("s_waitcnt vmcnt(0)" ::: "memory"); }
      SBAR();
    }
  }
#undef STAGE_A
#undef STAGE_B
#undef SBAR

  if (MODE == 0) {
    const int which = n0 >> 9, nb = n0 & 511;
    bf16* dst = which == 0 ? oq : (which == 1 ? ok : ov);
#pragma unroll
    for (int mt = 0; mt < 8; ++mt)
#pragma unroll
      for (int nt = 0; nt < 4; ++nt)
#pragma unroll
        for (int i = 0; i < 4; ++i) {
          int row = m0 + wr * 128 + mt * 16 + quad * 4 + i;
          int col = nb + wc * 64 + nt * 16 + lc;
          dst[(long)row * 512 + col] = f2bf(acc[mt][nt][i]);
        }
  } else {
#pragma unroll
    for (int mt = 0; mt < 8; ++mt)
#pragma unroll
      for (int nt = 0; nt < 4; ++nt)
#pragma unroll
        for (int i = 0; i < 4; ++i) {
          int row = m0 + wr * 128 + mt * 16 + quad * 4 + i;
          int col = n0 + wc * 64 + nt * 16 + lc;
          of[(long)row * 512 + col] = acc[mt][nt][i] + bias[col];
        }
  }
}

// ---------------------------------------------------------------------------
// Projection (atomic-free, 4 n-chunk bf16 partials):
//  z=0: kp_part[nc][bh][r][d] = sum_n k[b,n,h,d] * E[h,n,r]
//  z=1: vp_part[nc][bh][d][r] = sum_n v[b,n,h,d] * F[h,n,r]
// Big side (E/F^T, 256 x k) via global_load_lds; small side (K/V) LDS-
// transposed with XOR swizzle (2-way max on store & read).
// ---------------------------------------------------------------------------
__global__ __launch_bounds__(256) void proj_kernel(
    const bf16* __restrict__ Et_g, const bf16* __restrict__ Ft_g,
    const bf16* __restrict__ kb, const bf16* __restrict__ vb,
    bf16* __restrict__ kp_part, bf16* __restrict__ vp_part) {
  const int z = blockIdx.z;
  const bf16* Big = z ? Ft_g : Et_g;
  const bf16* src = z ? vb : kb;
  bf16* out = z ? vp_part : kp_part;
  const int bh = blockIdx.y, b = bh >> 3, h = bh & 7;
  const int nbase = blockIdx.x * 1024;
  __shared__ bf16 Eb[256][64];
  __shared__ bf16 Kt[64][72];
  const int t = threadIdx.x;
  const int w = t >> 6, l = t & 63, quad = l >> 4, lc = l & 15;
  const int ecol = (l & 7) * 8;
  const bf16* gE = Big + ((long)h * 256 + w * 64 + (l >> 3)) * 4096 + nbase + ecol;
  const int sn = t >> 3, sq = t & 7;
  const bf16* gK = src + (long)(b * 4096 + nbase + sn) * 512 + h * 64 + sq * 8;
  floatx4 acc[4][4] = {};
  for (int ks = 0; ks < 16; ++ks) {
    bf16x8 kv0 = *(const bf16x8*)(gK + (long)(ks * 64) * 512);
    bf16x8 kv1 = *(const bf16x8*)(gK + (long)(ks * 64 + 32) * 512);
    __syncthreads();   // previous iteration's LDS reads complete
#pragma unroll
    for (int i = 0; i < 8; ++i)
      async_copy16(gE + ks * 64 + (long)i * 8 * 4096, &Eb[w * 64 + i * 8][0]);
#pragma unroll
    for (int jj = 0; jj < 8; ++jj) Kt[sq * 8 + jj][sn ^ (sq * 8)] = kv0[jj];
#pragma unroll
    for (int jj = 0; jj < 8; ++jj) Kt[sq * 8 + jj][(32 + sn) ^ (sq * 8)] = kv1[jj];
    __syncthreads();
#pragma unroll
    for (int kk = 0; kk < 64; kk += 32) {
      bf16x8 af[4], bfr[4];
      if (z == 0) {
#pragma unroll
        for (int mt = 0; mt < 4; ++mt)
          af[mt] = *(const bf16x8*)&Eb[w * 64 + mt * 16 + lc][kk + quad * 8];
#pragma unroll
        for (int nt = 0; nt < 4; ++nt) {
          int d = nt * 16 + lc;
          bfr[nt] = *(const bf16x8*)&Kt[d][(kk + quad * 8) ^ ((d >> 3) << 3)];
        }
      } else {
#pragma unroll
        for (int mt = 0; mt < 4; ++mt) {
          int d = mt * 16 + lc;
          af[mt] = *(const bf16x8*)&Kt[d][(kk + quad * 8) ^ ((d >> 3) << 3)];
        }
#pragma unroll
        for (int nt = 0; nt < 4; ++nt)
          bfr[nt] = *(const bf16x8*)&Eb[w * 64 + nt * 16 + lc][kk + quad * 8];
      }
#pragma unroll
      for (int mt = 0; mt < 4; ++mt)
#pragma unroll
        for (int nt = 0; nt < 4; ++nt)
          acc[mt][nt] = MFMA16(af[mt], bfr[nt], acc[mt][nt]);
    }
  }
  bf16* obase = out + ((long)blockIdx.x * 64 + bh) * 16384;
  if (z == 0) {
#pragma unroll
    for (int mt = 0; mt < 4; ++mt)
#pragma unroll
      for (int nt = 0; nt < 4; ++nt)
#pragma unroll
        for (int i = 0; i < 4; ++i) {
          int r = w * 64 + mt * 16 + quad * 4 + i, d = nt * 16 + lc;
          obase[(long)r * 64 + d] = f2bf(acc[mt][nt][i]);
        }
  } else {
#pragma unroll
    for (int mt = 0; mt < 4; ++mt)
#pragma unroll
      for (int nt = 0; nt < 4; ++nt)
#pragma unroll
        for (int i = 0; i < 4; ++i) {
          int d = mt * 16 + quad * 4 + i, r = w * 64 + nt * 16 + lc;
          obase[(long)d * 256 + r] = f2bf(acc[mt][nt][i]);
        }
  }
}

// ---------------------------------------------------------------------------
// Partial reduce: kp/vp = sum of 4 proj n-chunk partials. fp32 accum, one
// bf16 round — numerics identical to the old fused staging. Pure-BW kernel.
// ---------------------------------------------------------------------------
__global__ void reduce_parts_kernel(const bf16* __restrict__ kp_part,
                                    const bf16* __restrict__ vp_part,
                                    bf16* __restrict__ kp, bf16* __restrict__ vp) {
  const bf16* src = blockIdx.z ? vp_part : kp_part;
  bf16* dst = blockIdx.z ? vp : kp;
  long i = ((long)blockIdx.x * 256 + threadIdx.x) * 8;
  bf16x8 a = *(const bf16x8*)(src + i);
  bf16x8 b = *(const bf16x8*)(src + 1048576 + i);
  bf16x8 c = *(const bf16x8*)(src + 2097152 + i);
  bf16x8 d = *(const bf16x8*)(src + 3145728 + i);
  bf16x8 o;
#pragma unroll
  for (int j = 0; j < 8; ++j)
    o[j] = f2bf(bf2f(a[j]) + bf2f(b[j]) + bf2f(c[j]) + bf2f(d[j]));
  *(bf16x8*)(dst + i) = o;
}

// ---------------------------------------------------------------------------
// Attention. Per (b,h,128 rows): S=q*kp^T (exp2-domain softmax, R=256);
// O=P_unnorm*vp, row-scaled by 1/sum afterwards. kp/vp pre-summed by
// reduce_parts_kernel; staging is a pure vector copy with T14 issue-early
// vp loads held in registers across GEMM-1.
// ---------------------------------------------------------------------------
__global__ __launch_bounds__(512) void attn_kernel(
    const bf16* __restrict__ qb, const bf16* __restrict__ kp,
    const bf16* __restrict__ vp, bf16* __restrict__ ao) {
  const int bx = blockIdx.x, h = blockIdx.y, b = blockIdx.z;
  const int bh = b * 8 + h;
  __shared__ __align__(16) char smem_u[36864];   // kpl 256x72 / vtl 64x264 union
  __shared__ bf16 Pc[2][128][40];
  bf16(*kpl)[72] = (bf16(*)[72])smem_u;
  bf16(*vtl)[264] = (bf16(*)[264])smem_u;
  const int t = threadIdx.x;
  const int w = t >> 6, l = t & 63, quad = l >> 4, lc = l & 15;

  // T14: issue vp loads now (held in regs across GEMM-1), stage kp to LDS.
  const bf16* pk = kp + (long)bh * 16384;
  const bf16* pv = vp + (long)bh * 16384;
  bf16x8 vreg[4];
#pragma unroll
  for (int j = 0; j < 4; ++j)
    vreg[j] = *(const bf16x8*)(pv + (long)(j * 512 + t) * 8);
#pragma unroll
  for (int j = 0; j < 4; ++j) {
    int e32 = j * 512 + t;
    *(bf16x8*)&kpl[e32 >> 3][(e32 & 7) * 8] = *(const bf16x8*)(pk + (long)e32 * 8);
  }
  __syncthreads();

  // GEMM-1: scores; q A-frags direct from global.
  const long qrow = (long)(b * 4096 + bx * 128 + w * 16 + lc) * 512 + h * 64;
  floatx4 acc[16] = {};
#pragma unroll
  for (int kk = 0; kk < 64; kk += 32) {
    bf16x8 a = *(const bf16x8*)(qb + qrow + kk + quad * 8);
#pragma unroll
    for (int nt = 0; nt < 16; ++nt) {
      bf16x8 bfr = *(const bf16x8*)&kpl[nt * 16 + lc][kk + quad * 8];
      acc[nt] = MFMA16(a, bfr, acc[nt]);
    }
  }
  __syncthreads();   // kpl reads done; union becomes vtl

  {  // write vp tile (64x256 bf16) from the pre-issued registers
#pragma unroll
    for (int j = 0; j < 4; ++j) {
      int e32 = j * 512 + t;
      *(bf16x8*)&vtl[e32 >> 5][(e32 & 31) * 8] = vreg[j];
    }
  }

  // softmax in exp2 domain: scale = (1/8) * log2(e); P left unnormalized,
  // row 1/sum applied to acc2 after PV (commutes with the matmul).
  constexpr float SC = 0.18033688011112042f;
  float mx[4] = {-1e30f, -1e30f, -1e30f, -1e30f};
#pragma unroll
  for (int nt = 0; nt < 16; ++nt)
#pragma unroll
    for (int i = 0; i < 4; ++i) {
      acc[nt][i] *= SC;
      mx[i] = fmaxf(mx[i], acc[nt][i]);
    }
#pragma unroll
  for (int m = 1; m <= 8; m <<= 1)
#pragma unroll
    for (int i = 0; i < 4; ++i) mx[i] = fmaxf(mx[i], __shfl_xor(mx[i], m, 64));
  float sm[4] = {0.f, 0.f, 0.f, 0.f};
#pragma unroll
  for (int nt = 0; nt < 16; ++nt)
#pragma unroll
    for (int i = 0; i < 4; ++i) {
      float pp = __builtin_amdgcn_exp2f(acc[nt][i] - mx[i]);
      acc[nt][i] = pp;
      sm[i] += pp;
    }
#pragma unroll
  for (int m = 1; m <= 8; m <<= 1)
#pragma unroll
    for (int i = 0; i < 4; ++i) sm[i] += __shfl_xor(sm[i], m, 64);
  float inv[4];
#pragma unroll
  for (int i = 0; i < 4; ++i) inv[i] = 1.0f / sm[i];

  // GEMM-2: O = P*vp; P chunks (32 r) double-buffered, 1 barrier per chunk.
  floatx4 acc2[4] = {};
  for (int rs = 0; rs < 8; ++rs) {
    const int buf = rs & 1;
#pragma unroll
    for (int u = 0; u < 2; ++u) {
      int nt = rs * 2 + u;
#pragma unroll
      for (int i = 0; i < 4; ++i)
        Pc[buf][w * 16 + quad * 4 + i][u * 16 + lc] = f2bf(acc[nt][i]);
    }
    __syncthreads();   // also covers vtl staging on rs==0
    bf16x8 a2 = *(const bf16x8*)&Pc[buf][w * 16 + lc][quad * 8];
#pragma unroll
    for (int nt = 0; nt < 4; ++nt) {
      bf16x8 b2 = *(const bf16x8*)&vtl[nt * 16 + lc][rs * 32 + quad * 8];
      acc2[nt] = MFMA16(a2, b2, acc2[nt]);
    }
  }

#pragma unroll
  for (int nt = 0; nt < 4; ++nt)
#pragma unroll
    for (int i = 0; i < 4; ++i) {
      int row = bx * 128 + w * 16 + quad * 4 + i;
      int d = nt * 16 + lc;
      ao[(long)(b * 4096 + row) * 512 + h * 64 + d] = f2bf(acc2[nt][i] * inv[i]);
    }
}

// ---------------------------------------------------------------------------
extern "C" void kernel_launch(void* const* d_in, const int* in_sizes, int n_in,
                              void* d_out, int out_size, void* d_ws, size_t ws_size,
                              hipStream_t stream) {
  const float* x  = (const float*)d_in[0];
  const float* wq = (const float*)d_in[1];
  const float* wk = (const float*)d_in[2];
  const float* wv = (const float*)d_in[3];
  const float* E  = (const float*)d_in[4];
  const float* F  = (const float*)d_in[5];
  const float* wd = (const float*)d_in[6];
  const float* bd = (const float*)d_in[7];
  float* out = (float*)d_out;

  // workspace layout (bytes); total 186,646,528
  char* ws = (char*)d_ws;
  bf16* x_bf    = (bf16*)(ws + 0);            // 33,554,432 (dead after QKV -> attn_o)
  bf16* q_bf    = (bf16*)(ws + 33554432l);    // 33,554,432
  bf16* k_bf    = (bf16*)(ws + 67108864l);    // 33,554,432 (dead after proj -> kp/vp)
  bf16* v_bf    = (bf16*)(ws + 100663296l);   // 33,554,432
  bf16* Et_g    = (bf16*)(ws + 134217728l);   // 16,777,216  (H,R,N)
  bf16* Ft_g    = (bf16*)(ws + 150994944l);   // 16,777,216
  bf16* Wt      = (bf16*)(ws + 167772160l);   //  1,572,864  [wq^T|wk^T|wv^T] (n,k)
  bf16* wdT     = (bf16*)(ws + 169345024l);   //    524,288
  bf16* kp_part = (bf16*)(ws + 169869312l);   //  8,388,608  [4][bh][r][d]
  bf16* vp_part = (bf16*)(ws + 178257920l);   //  8,388,608  [4][bh][d][r]
  bf16* attn_o  = x_bf;
  bf16* kp_sum  = k_bf;                       //  2,097,152  (aliases dead k_bf)
  bf16* vp_sum  = (bf16*)(ws + 67108864l + 2097152l);

  static bool attr_done = false;
  if (!attr_done) {
    hipFuncSetAttribute((const void*)gemm256_kernel<0>,
                        hipFuncAttributeMaxDynamicSharedMemorySize, 131072);
    hipFuncSetAttribute((const void*)gemm256_kernel<1>,
                        hipFuncAttributeMaxDynamicSharedMemorySize, 131072);
    attr_done = true;
  }

  dim3 tb(32, 8);
  cvt_bf16_kernel<<<8192, 256, 0, stream>>>(x, x_bf);
  transpose_w4_kernel<<<dim3(16, 16, 4), tb, 0, stream>>>(wq, wk, wv, wd, Wt, wdT);
  transpose_ef_kernel<<<dim3(128, 8, 16), tb, 0, stream>>>(E, F, Et_g, Ft_g);

  gemm256_kernel<0><<<768, 512, 131072, stream>>>(x_bf, Wt, q_bf, k_bf, v_bf, nullptr, nullptr);
  proj_kernel<<<dim3(4, 64, 2), 256, 0, stream>>>(Et_g, Ft_g, k_bf, v_bf, kp_part, vp_part);
  reduce_parts_kernel<<<dim3(512, 1, 2), 256, 0, stream>>>(kp_part, vp_part, kp_sum, vp_sum);
  attn_kernel<<<dim3(32, 8, 8), 512, 0, stream>>>(q_bf, kp_sum, vp_sum, attn_o);
  gemm256_kernel<1><<<256, 512, 131072, stream>>>(attn_o, wdT, nullptr, nullptr, nullptr, out, bd);
}